// Round 4
// baseline (671.339 us; speedup 1.0000x reference)
//
#include <hip/hip_runtime.h>

// B=4, C=512, H=W=64 -> N=4096 tokens, KEY_DIM=VALUE_DIM=512.
// Pipeline (all matmuls on v_mfma_f32_16x16x32_bf16, fp32 accum):
//   K1 qkv_proj   : Qt,Kt (B,N,D) bf16 token-major; Vd (B,D,N) bf16 d-major (ws).
//   K2 attn_lsum_p: S=QK^T/sqrt(D); store Pexp=exp(S) bf16 to ws as [b][q][i];
//                   accumulate l_j via fp32 atomics. Key-split 4 -> 1024 WGs.
//   K3 attn_pv    : O = V . Pexp^T, D-SPLIT (each output owned by ONE block ->
//                   plain stores, no atomics). Both operands direct from global,
//                   no LDS/barriers, explicit next-chunk register prefetch.
//   K4 colsum_k   : scores[i] = sum_q Pexp[q,i]/l[q] — single streaming pass
//                   over P, 1 atomic per element per block at the end.
// No max-subtraction in softmax: logits ~ N(0,1), exp() can't overflow.
// ws: QKV 50.3 MB + l 64 KB + Pexp 134.2 MB = 184.7 MB.

typedef short bf16x8 __attribute__((ext_vector_type(8)));
typedef float f32x4 __attribute__((ext_vector_type(4)));

#define NTOK 4096
#define DDIM 512
#define NB   4

__device__ __forceinline__ unsigned short f32_bf16(float f) {
  union { float f; unsigned u; } v; v.f = f;
  unsigned r = v.u + 0x7FFFu + ((v.u >> 16) & 1u);  // RNE
  return (unsigned short)(r >> 16);
}

__device__ __forceinline__ float bf16_f32(short s) {
  union { unsigned u; float f; } v;
  v.u = ((unsigned)(unsigned short)s) << 16;
  return v.f;
}

// ---------------------------------------------------------------------------
// K1: QKV projection.  Q[n,d] = sum_c x[c,n] * Wq[d,c]  (x is (C,N) per batch)
// ---------------------------------------------------------------------------
__global__ __launch_bounds__(256, 4) void qkv_proj(
    const float* __restrict__ x,
    const float* __restrict__ Wq,
    const float* __restrict__ Wk,
    const float* __restrict__ Wv,
    unsigned short* __restrict__ Qt,
    unsigned short* __restrict__ Kt,
    unsigned short* __restrict__ Vd)
{
  const int nt0 = blockIdx.x * 64;   // token tile
  const int d0  = blockIdx.y * 64;   // feature tile
  const int b   = blockIdx.z;
  const int tid = threadIdx.x;
  const int wave = tid >> 6;
  const int lane = tid & 63;
  const int l15  = lane & 15;
  const int quad = lane >> 4;

  __shared__ __align__(16) unsigned short Xt[64 * 40];     // [token][c]
  __shared__ __align__(16) unsigned short Wl[3][64 * 40];  // [q/k/v][d][c]

  f32x4 aq[4], ak[4], av[4];
#pragma unroll
  for (int i = 0; i < 4; ++i) {
    aq[i] = (f32x4){0.f,0.f,0.f,0.f};
    ak[i] = (f32x4){0.f,0.f,0.f,0.f};
    av[i] = (f32x4){0.f,0.f,0.f,0.f};
  }

  const float* xb = x + (size_t)b * DDIM * NTOK + nt0;
  const int xn  = tid & 63;
  const int xc8 = tid >> 6;
  const int wc8 = tid & 3;
  const int wdd = tid >> 2;

  for (int cc = 0; cc < DDIM; cc += 32) {
    __syncthreads();
    {
      bf16x8 t;
#pragma unroll
      for (int j = 0; j < 8; ++j)
        t[j] = (short)f32_bf16(xb[(size_t)(cc + xc8 * 8 + j) * NTOK + xn]);
      *(bf16x8*)(&Xt[xn * 40 + xc8 * 8]) = t;
    }
    {
      const float* wsrc[3] = {Wq, Wk, Wv};
#pragma unroll
      for (int m = 0; m < 3; ++m) {
        const float* src = wsrc[m] + (size_t)(d0 + wdd) * DDIM + cc + wc8 * 8;
        bf16x8 t;
#pragma unroll
        for (int j = 0; j < 8; ++j) t[j] = (short)f32_bf16(src[j]);
        *(bf16x8*)(&Wl[m][wdd * 40 + wc8 * 8]) = t;
      }
    }
    __syncthreads();

    bf16x8 xa  = *(const bf16x8*)(&Xt[(wave * 16 + l15) * 40 + quad * 8]);
    bf16x8 wva = *(const bf16x8*)(&Wl[2][(wave * 16 + l15) * 40 + quad * 8]);
#pragma unroll
    for (int nt = 0; nt < 4; ++nt) {
      bf16x8 wqf = *(const bf16x8*)(&Wl[0][(nt * 16 + l15) * 40 + quad * 8]);
      bf16x8 wkf = *(const bf16x8*)(&Wl[1][(nt * 16 + l15) * 40 + quad * 8]);
      bf16x8 xbf = *(const bf16x8*)(&Xt[(nt * 16 + l15) * 40 + quad * 8]);
      aq[nt] = __builtin_amdgcn_mfma_f32_16x16x32_bf16(xa,  wqf, aq[nt], 0, 0, 0);
      ak[nt] = __builtin_amdgcn_mfma_f32_16x16x32_bf16(xa,  wkf, ak[nt], 0, 0, 0);
      av[nt] = __builtin_amdgcn_mfma_f32_16x16x32_bf16(wva, xbf, av[nt], 0, 0, 0);
    }
  }

#pragma unroll
  for (int nt = 0; nt < 4; ++nt) {
#pragma unroll
    for (int r = 0; r < 4; ++r) {
      const int tokq = nt0 + wave * 16 + quad * 4 + r;
      const int dq   = d0 + nt * 16 + l15;
      Qt[((size_t)b * NTOK + tokq) * DDIM + dq] = f32_bf16(aq[nt][r]);
      Kt[((size_t)b * NTOK + tokq) * DDIM + dq] = f32_bf16(ak[nt][r]);
      const int dv   = d0 + wave * 16 + quad * 4 + r;
      const int tokv = nt0 + nt * 16 + l15;
      Vd[((size_t)b * DDIM + dv) * NTOK + tokv] = f32_bf16(av[nt][r]);
    }
  }
}

// ---------------------------------------------------------------------------
#define BK   64
#define DSUB 256
#define KROW 264   // 256 + 8 pad
#define SCALE 0.044194173824159216f  // 1/sqrt(512)

__device__ __forceinline__ void stage_k(const unsigned short* __restrict__ src,
                                        unsigned short* __restrict__ Klds,
                                        int tid, int dsi) {
#pragma unroll
  for (int it = 0; it < 8; ++it) {
    const int li = tid + it * 256;
    const int ri = li >> 5;
    const int c8 = li & 31;
    *(bf16x8*)(&Klds[ri * KROW + c8 * 8]) =
        *(const bf16x8*)(src + (size_t)ri * DDIM + dsi * DSUB + c8 * 8);
  }
}

// ---------------------------------------------------------------------------
// K2: QK^T -> Pexp store + row-sum atomics. Grid (64, 4 kparts, NB) = 1024 WGs.
// ---------------------------------------------------------------------------
__global__ __launch_bounds__(256, 4) void attn_lsum_p(
    const unsigned short* __restrict__ Qt,
    const unsigned short* __restrict__ Kt,
    unsigned short* __restrict__ Pst,
    float* __restrict__ lsum_g)
{
  const int q0 = blockIdx.x * 64;
  const int k0 = blockIdx.y * (NTOK / 4);
  const int b  = blockIdx.z;
  const int tid = threadIdx.x;
  const int wave = tid >> 6;
  const int lane = tid & 63;
  const int l15  = lane & 15;
  const int quad = lane >> 4;

  __shared__ __align__(16) unsigned short Klds[BK * KROW];  // 33792 B

  bf16x8 qf[16];
  {
    const unsigned short* qp =
        Qt + ((size_t)b * NTOK + q0 + wave * 16 + l15) * DDIM + quad * 8;
#pragma unroll
    for (int dc = 0; dc < 16; ++dc) qf[dc] = *(const bf16x8*)(qp + dc * 32);
  }

  const unsigned short* kb = Kt + (size_t)b * NTOK * DDIM;
  unsigned short* Pb = Pst + (size_t)b * NTOK * NTOK;
  float ls[4] = {0.f, 0.f, 0.f, 0.f};

  for (int kc = 0; kc < (NTOK / 4) / BK; ++kc) {
    const int i0 = k0 + kc * BK;
    const unsigned short* ksrc = kb + (size_t)i0 * DDIM;
    f32x4 sacc[4];
#pragma unroll
    for (int i = 0; i < 4; ++i) sacc[i] = (f32x4){0.f,0.f,0.f,0.f};
#pragma unroll
    for (int dsi = 0; dsi < 2; ++dsi) {
      __syncthreads();
      stage_k(ksrc, Klds, tid, dsi);
      __syncthreads();
#pragma unroll
      for (int dc = 0; dc < 8; ++dc) {
        const int ko = dc * 32 + quad * 8;
        const bf16x8 a = qf[dsi * 8 + dc];
#pragma unroll
        for (int nt = 0; nt < 4; ++nt) {
          bf16x8 kf = *(const bf16x8*)(&Klds[(nt * 16 + l15) * KROW + ko]);
          sacc[nt] = __builtin_amdgcn_mfma_f32_16x16x32_bf16(a, kf, sacc[nt], 0, 0, 0);
        }
      }
    }
    // Pexp = exp(s*scale): store bf16 (C-layout row=q=quad*4+r, col=i=l15)
#pragma unroll
    for (int nt = 0; nt < 4; ++nt) {
#pragma unroll
      for (int r = 0; r < 4; ++r) {
        const float e = __expf(sacc[nt][r] * SCALE);
        ls[r] += e;
        Pb[(size_t)(q0 + wave * 16 + quad * 4 + r) * NTOK + i0 + nt * 16 + l15] =
            f32_bf16(e);
      }
    }
  }

#pragma unroll
  for (int r = 0; r < 4; ++r) {
    float v = ls[r];
    v += __shfl_xor(v, 1);
    v += __shfl_xor(v, 2);
    v += __shfl_xor(v, 4);
    v += __shfl_xor(v, 8);
    if (l15 == 0)
      unsafeAtomicAdd(&lsum_g[(size_t)b * NTOK + q0 + wave * 16 + quad * 4 + r], v);
  }
}

// ---------------------------------------------------------------------------
// K3: O = V . Pexp^T, d-split. Grid (64 q0, 4 dpart, NB) = 1024 WGs (4/CU).
// Wave w owns d in [dpart*128 + w*32, +32). No LDS, no barriers, no atomics.
// Per 32-key chunk: 6 global dwordx4 (prefetched one chunk ahead) + 8 MFMA.
// ---------------------------------------------------------------------------
__global__ __launch_bounds__(256, 4) void attn_pv(
    const unsigned short* __restrict__ Pst,
    const unsigned short* __restrict__ Vd,
    const float* __restrict__ lsum_g,
    float* __restrict__ out)
{
  const int q0    = blockIdx.x * 64;
  const int dpart = blockIdx.y;
  const int b     = blockIdx.z;
  const int tid  = threadIdx.x;
  const int wave = tid >> 6;
  const int lane = tid & 63;
  const int l15  = lane & 15;
  const int quad = lane >> 4;

  const int dbase = dpart * 128 + wave * 32;
  const unsigned short* Pb = Pst + (size_t)b * NTOK * NTOK;
  const unsigned short* vb =
      Vd + ((size_t)b * DDIM + dbase + l15) * NTOK + quad * 8;
  const unsigned short* pb = Pb + (size_t)(q0 + l15) * NTOK + quad * 8;

  float rlv[4];
#pragma unroll
  for (int nt = 0; nt < 4; ++nt)
    rlv[nt] = 1.0f / lsum_g[(size_t)b * NTOK + q0 + nt * 16 + l15];

  f32x4 o[2][4];
#pragma unroll
  for (int i = 0; i < 2; ++i)
#pragma unroll
    for (int j = 0; j < 4; ++j) o[i][j] = (f32x4){0.f,0.f,0.f,0.f};

  bf16x8 pc[4], vc[2], pn[4], vn[2];
#pragma unroll
  for (int nt = 0; nt < 4; ++nt)
    pc[nt] = *(const bf16x8*)(pb + (size_t)(nt * 16) * NTOK);
#pragma unroll
  for (int mt = 0; mt < 2; ++mt)
    vc[mt] = *(const bf16x8*)(vb + (size_t)(mt * 16) * NTOK);

#pragma unroll 2
  for (int kc = 0; kc < 127; ++kc) {
    const int i1 = (kc + 1) * 32;
    // prefetch next chunk while current MFMAs run
#pragma unroll
    for (int nt = 0; nt < 4; ++nt)
      pn[nt] = *(const bf16x8*)(pb + (size_t)(nt * 16) * NTOK + i1);
#pragma unroll
    for (int mt = 0; mt < 2; ++mt)
      vn[mt] = *(const bf16x8*)(vb + (size_t)(mt * 16) * NTOK + i1);
#pragma unroll
    for (int mt = 0; mt < 2; ++mt)
#pragma unroll
      for (int nt = 0; nt < 4; ++nt)
        o[mt][nt] = __builtin_amdgcn_mfma_f32_16x16x32_bf16(vc[mt], pc[nt], o[mt][nt], 0, 0, 0);
#pragma unroll
    for (int nt = 0; nt < 4; ++nt) pc[nt] = pn[nt];
#pragma unroll
    for (int mt = 0; mt < 2; ++mt) vc[mt] = vn[mt];
  }
#pragma unroll
  for (int mt = 0; mt < 2; ++mt)
#pragma unroll
    for (int nt = 0; nt < 4; ++nt)
      o[mt][nt] = __builtin_amdgcn_mfma_f32_16x16x32_bf16(vc[mt], pc[nt], o[mt][nt], 0, 0, 0);

  // epilogue: plain coalesced stores, 1/l folded in (per output column q).
  float* ob = out + ((size_t)b * DDIM + dbase) * NTOK + q0;
#pragma unroll
  for (int mt = 0; mt < 2; ++mt)
#pragma unroll
    for (int nt = 0; nt < 4; ++nt)
#pragma unroll
      for (int r = 0; r < 4; ++r)
        ob[(size_t)(mt * 16 + quad * 4 + r) * NTOK + nt * 16 + l15] =
            o[mt][nt][r] * rlv[nt];
}

// ---------------------------------------------------------------------------
// K4: scores[b][i] = sum_q Pexp[b][q][i] / l[b][q].  One streaming pass over P.
// Grid (2 i-chunks, 64 q-chunks, NB) = 512 WGs; thread owns 8 consecutive i.
// ---------------------------------------------------------------------------
__global__ __launch_bounds__(256, 8) void colsum_k(
    const unsigned short* __restrict__ Pst,
    const float* __restrict__ lsum_g,
    float* __restrict__ scores_out)
{
  const int ic = blockIdx.x;
  const int qc = blockIdx.y;
  const int b  = blockIdx.z;
  const int i_base = ic * 2048 + threadIdx.x * 8;

  const unsigned short* Pb = Pst + (size_t)b * NTOK * NTOK + i_base;
  const float* lb = lsum_g + (size_t)b * NTOK;

  float acc[8];
#pragma unroll
  for (int j = 0; j < 8; ++j) acc[j] = 0.f;

  for (int q = qc * 64; q < qc * 64 + 64; ++q) {
    const float rl = 1.0f / lb[q];  // wave-uniform scalar
    const bf16x8 p = *(const bf16x8*)(Pb + (size_t)q * NTOK);
#pragma unroll
    for (int j = 0; j < 8; ++j) acc[j] = fmaf(bf16_f32(p[j]), rl, acc[j]);
  }
#pragma unroll
  for (int j = 0; j < 8; ++j)
    unsafeAtomicAdd(&scores_out[(size_t)b * NTOK + i_base + j], acc[j]);
}

// ---------------------------------------------------------------------------
extern "C" void kernel_launch(void* const* d_in, const int* in_sizes, int n_in,
                              void* d_out, int out_size, void* d_ws, size_t ws_size,
                              hipStream_t stream) {
  const float* x  = (const float*)d_in[0];
  const float* Wk = (const float*)d_in[1];  // dict order: x, Wk, Wq, Wv
  const float* Wq = (const float*)d_in[2];
  const float* Wv = (const float*)d_in[3];

  float* out = (float*)d_out;
  float* scores_out = out + (size_t)NB * DDIM * NTOK;  // tail of d_out

  const size_t mat_elems = (size_t)NB * NTOK * DDIM;   // 8388608
  unsigned short* Qt = (unsigned short*)d_ws;
  unsigned short* Kt = Qt + mat_elems;
  unsigned short* Vd = Kt + mat_elems;
  float* lbuf = (float*)(Vd + mat_elems);              // 64 KB
  unsigned short* Pst = (unsigned short*)(lbuf + (size_t)NB * NTOK);  // 134.2 MB

  hipMemsetAsync(lbuf, 0, (size_t)NB * NTOK * sizeof(float), stream);
  hipMemsetAsync(scores_out, 0, (size_t)NB * NTOK * sizeof(float), stream);

  dim3 g1(NTOK / 64, DDIM / 64, NB);
  qkv_proj<<<g1, 256, 0, stream>>>(x, Wq, Wk, Wv, Qt, Kt, Vd);

  dim3 g2(NTOK / 64, 4, NB);
  attn_lsum_p<<<g2, 256, 0, stream>>>(Qt, Kt, Pst, lbuf);

  dim3 g3(NTOK / 64, 4, NB);
  attn_pv<<<g3, 256, 0, stream>>>(Pst, Vd, lbuf, out);

  dim3 g4(2, 64, NB);
  colsum_k<<<g4, 256, 0, stream>>>(Pst, lbuf, scores_out);
}

// Round 5
// 411.252 us; speedup vs baseline: 1.6324x; 1.6324x over previous
//
#include <hip/hip_runtime.h>

// B=4, C=512, H=W=64 -> N=4096 tokens, KEY_DIM=VALUE_DIM=512.
// Pipeline (all matmuls on v_mfma_f32_16x16x32_bf16, fp32 accum):
//   K1 qkv_proj   : Qt,Kt (B,N,D) bf16 token-major; V in FRAGMENT-TILE layout
//                   Vt[b][dblk(32)][ic(128)][lane(64)][8]  (d=dblk*16+(lane&15),
//                   i=ic*32+(lane>>4)*8+j) -> K3 A-operand loads are lane*16B
//                   contiguous (1KB/instr, fully coalesced).
//   K2 attn_lsum_p: S=QK^T/sqrt(D); Pexp=exp(S) stored in fragment-tile layout
//                   Pt[b][q0b(64)][ic(128)][nt(4)][lane(64)][8] (q=q0b*64+nt*16+
//                   (lane&15), i=ic*32+(lane>>4)*8+j); l_j via fp32 atomics.
//   K3 attn_pv    : O = V.Pexp^T; block=64q x 256d (grid 64x2xB, 2 blk/CU);
//                   all fragment loads 1KB-coalesced; no LDS/barriers/atomics.
//   K4 colsum_k   : scores[i] = sum_q Pexp[q,i]/l[q]; tile-layout streaming
//                   reduce, LDS cross-wave merge, plain stores (no atomics).
// No max-subtraction in softmax: logits ~ N(0,1), exp() can't overflow.
// ws: QKV 50.3 MB + l 64 KB + Pexp 134.2 MB = 184.7 MB.

typedef short bf16x8 __attribute__((ext_vector_type(8)));
typedef float f32x4 __attribute__((ext_vector_type(4)));

#define NTOK 4096
#define DDIM 512
#define NB   4

__device__ __forceinline__ unsigned short f32_bf16(float f) {
  union { float f; unsigned u; } v; v.f = f;
  unsigned r = v.u + 0x7FFFu + ((v.u >> 16) & 1u);  // RNE
  return (unsigned short)(r >> 16);
}

__device__ __forceinline__ float bf16_f32(short s) {
  union { unsigned u; float f; } v;
  v.u = ((unsigned)(unsigned short)s) << 16;
  return v.f;
}

// ---------------------------------------------------------------------------
// K1: QKV projection.  Q[n,d] = sum_c x[c,n] * Wq[d,c]  (x is (C,N) per batch)
// ---------------------------------------------------------------------------
__global__ __launch_bounds__(256, 4) void qkv_proj(
    const float* __restrict__ x,
    const float* __restrict__ Wq,
    const float* __restrict__ Wk,
    const float* __restrict__ Wv,
    unsigned short* __restrict__ Qt,
    unsigned short* __restrict__ Kt,
    unsigned short* __restrict__ Vt)
{
  const int nt0 = blockIdx.x * 64;   // token tile
  const int d0  = blockIdx.y * 64;   // feature tile
  const int b   = blockIdx.z;
  const int tid = threadIdx.x;
  const int wave = tid >> 6;
  const int lane = tid & 63;
  const int l15  = lane & 15;
  const int quad = lane >> 4;

  __shared__ __align__(16) unsigned short Xt[64 * 40];     // [token][c]
  __shared__ __align__(16) unsigned short Wl[3][64 * 40];  // [q/k/v][d][c]

  f32x4 aq[4], ak[4], av[4];
#pragma unroll
  for (int i = 0; i < 4; ++i) {
    aq[i] = (f32x4){0.f,0.f,0.f,0.f};
    ak[i] = (f32x4){0.f,0.f,0.f,0.f};
    av[i] = (f32x4){0.f,0.f,0.f,0.f};
  }

  const float* xb = x + (size_t)b * DDIM * NTOK + nt0;
  const int xn  = tid & 63;
  const int xc8 = tid >> 6;
  const int wc8 = tid & 3;
  const int wdd = tid >> 2;

  for (int cc = 0; cc < DDIM; cc += 32) {
    __syncthreads();
    {
      bf16x8 t;
#pragma unroll
      for (int j = 0; j < 8; ++j)
        t[j] = (short)f32_bf16(xb[(size_t)(cc + xc8 * 8 + j) * NTOK + xn]);
      *(bf16x8*)(&Xt[xn * 40 + xc8 * 8]) = t;
    }
    {
      const float* wsrc[3] = {Wq, Wk, Wv};
#pragma unroll
      for (int m = 0; m < 3; ++m) {
        const float* src = wsrc[m] + (size_t)(d0 + wdd) * DDIM + cc + wc8 * 8;
        bf16x8 t;
#pragma unroll
        for (int j = 0; j < 8; ++j) t[j] = (short)f32_bf16(src[j]);
        *(bf16x8*)(&Wl[m][wdd * 40 + wc8 * 8]) = t;
      }
    }
    __syncthreads();

    bf16x8 xa  = *(const bf16x8*)(&Xt[(wave * 16 + l15) * 40 + quad * 8]);
    bf16x8 wva = *(const bf16x8*)(&Wl[2][(wave * 16 + l15) * 40 + quad * 8]);
#pragma unroll
    for (int nt = 0; nt < 4; ++nt) {
      bf16x8 wqf = *(const bf16x8*)(&Wl[0][(nt * 16 + l15) * 40 + quad * 8]);
      bf16x8 wkf = *(const bf16x8*)(&Wl[1][(nt * 16 + l15) * 40 + quad * 8]);
      bf16x8 xbf = *(const bf16x8*)(&Xt[(nt * 16 + l15) * 40 + quad * 8]);
      aq[nt] = __builtin_amdgcn_mfma_f32_16x16x32_bf16(xa,  wqf, aq[nt], 0, 0, 0);
      ak[nt] = __builtin_amdgcn_mfma_f32_16x16x32_bf16(xa,  wkf, ak[nt], 0, 0, 0);
      av[nt] = __builtin_amdgcn_mfma_f32_16x16x32_bf16(wva, xbf, av[nt], 0, 0, 0);
    }
  }

#pragma unroll
  for (int nt = 0; nt < 4; ++nt) {
#pragma unroll
    for (int r = 0; r < 4; ++r) {
      const int tokq = nt0 + wave * 16 + quad * 4 + r;
      const int dq   = d0 + nt * 16 + l15;
      Qt[((size_t)b * NTOK + tokq) * DDIM + dq] = f32_bf16(aq[nt][r]);
      Kt[((size_t)b * NTOK + tokq) * DDIM + dq] = f32_bf16(ak[nt][r]);
      // V fragment-tile store: d = d0+wave*16+quad*4+r, i = nt0+nt*16+l15
      const int dblk  = (d0 >> 4) + wave;
      const int ic    = (nt0 >> 5) + (nt >> 1);
      const int laneV = ((nt & 1) * 2 + (l15 >> 3)) * 16 + quad * 4 + r;
      Vt[(size_t)b * DDIM * NTOK +
         ((size_t)(dblk * 128 + ic) * 64 + laneV) * 8 + (l15 & 7)] =
          f32_bf16(av[nt][r]);
    }
  }
}

// ---------------------------------------------------------------------------
#define BK   64
#define DSUB 256
#define KROW 264   // 256 + 8 pad
#define SCALE 0.044194173824159216f  // 1/sqrt(512)

__device__ __forceinline__ void stage_k(const unsigned short* __restrict__ src,
                                        unsigned short* __restrict__ Klds,
                                        int tid, int dsi) {
#pragma unroll
  for (int it = 0; it < 8; ++it) {
    const int li = tid + it * 256;
    const int ri = li >> 5;
    const int c8 = li & 31;
    *(bf16x8*)(&Klds[ri * KROW + c8 * 8]) =
        *(const bf16x8*)(src + (size_t)ri * DDIM + dsi * DSUB + c8 * 8);
  }
}

// ---------------------------------------------------------------------------
// K2: QK^T -> Pexp (fragment-tile layout) + row-sum atomics.
// Grid (64, 4 kparts, NB) = 1024 WGs (4/CU).
// ---------------------------------------------------------------------------
__global__ __launch_bounds__(256, 4) void attn_lsum_p(
    const unsigned short* __restrict__ Qt,
    const unsigned short* __restrict__ Kt,
    unsigned short* __restrict__ Pt,
    float* __restrict__ lsum_g)
{
  const int q0 = blockIdx.x * 64;
  const int k0 = blockIdx.y * (NTOK / 4);
  const int b  = blockIdx.z;
  const int tid = threadIdx.x;
  const int wave = tid >> 6;
  const int lane = tid & 63;
  const int l15  = lane & 15;
  const int quad = lane >> 4;

  __shared__ __align__(16) unsigned short Klds[BK * KROW];  // 33792 B

  bf16x8 qf[16];
  {
    const unsigned short* qp =
        Qt + ((size_t)b * NTOK + q0 + wave * 16 + l15) * DDIM + quad * 8;
#pragma unroll
    for (int dc = 0; dc < 16; ++dc) qf[dc] = *(const bf16x8*)(qp + dc * 32);
  }

  const unsigned short* kb = Kt + (size_t)b * NTOK * DDIM;
  // per-(b, q0-block) P tile region: 128 ic * 4 nt * 512 = 262144 elems
  unsigned short* Pq = Pt + (size_t)b * NTOK * NTOK + (size_t)(q0 >> 6) * 262144;
  float ls[4] = {0.f, 0.f, 0.f, 0.f};

  for (int kc = 0; kc < (NTOK / 4) / BK; ++kc) {
    const int i0 = k0 + kc * BK;
    const unsigned short* ksrc = kb + (size_t)i0 * DDIM;
    f32x4 sacc[4];
#pragma unroll
    for (int i = 0; i < 4; ++i) sacc[i] = (f32x4){0.f,0.f,0.f,0.f};
#pragma unroll
    for (int dsi = 0; dsi < 2; ++dsi) {
      __syncthreads();
      stage_k(ksrc, Klds, tid, dsi);
      __syncthreads();
#pragma unroll
      for (int dc = 0; dc < 8; ++dc) {
        const int ko = dc * 32 + quad * 8;
        const bf16x8 a = qf[dsi * 8 + dc];
#pragma unroll
        for (int nt = 0; nt < 4; ++nt) {
          bf16x8 kf = *(const bf16x8*)(&Klds[(nt * 16 + l15) * KROW + ko]);
          sacc[nt] = __builtin_amdgcn_mfma_f32_16x16x32_bf16(a, kf, sacc[nt], 0, 0, 0);
        }
      }
    }
    // Pexp stores in fragment-tile layout: q = q0+wave*16+quad*4+r,
    // i = i0+nt*16+l15 -> ic=(i0>>5)+(nt>>1), laneP=((nt&1)*2+(l15>>3))*16+quad*4+r
#pragma unroll
    for (int nt = 0; nt < 4; ++nt) {
      const int ic    = (i0 >> 5) + (nt >> 1);
      const int laneP = ((nt & 1) * 2 + (l15 >> 3)) * 16 + quad * 4;
#pragma unroll
      for (int r = 0; r < 4; ++r) {
        const float e = __expf(sacc[nt][r] * SCALE);
        ls[r] += e;
        Pq[((size_t)(ic * 4 + wave) * 64 + laneP + r) * 8 + (l15 & 7)] = f32_bf16(e);
      }
    }
  }

#pragma unroll
  for (int r = 0; r < 4; ++r) {
    float v = ls[r];
    v += __shfl_xor(v, 1);
    v += __shfl_xor(v, 2);
    v += __shfl_xor(v, 4);
    v += __shfl_xor(v, 8);
    if (l15 == 0)
      unsafeAtomicAdd(&lsum_g[(size_t)b * NTOK + q0 + wave * 16 + quad * 4 + r], v);
  }
}

// ---------------------------------------------------------------------------
// K3: O = V.Pexp^T.  Grid (64 q0b, 2 dpart, NB) = 512 WGs (2/CU, 8 waves).
// Wave owns 64 d x 64 q.  Per ic: 8 coalesced 1-KB loads + 16 MFMA.
// No LDS, no barriers, no atomics; plain coalesced epilogue stores.
// ---------------------------------------------------------------------------
__global__ __launch_bounds__(256, 2) void attn_pv(
    const unsigned short* __restrict__ Pt,
    const unsigned short* __restrict__ Vt,
    const float* __restrict__ lsum_g,
    float* __restrict__ out)
{
  const int q0b   = blockIdx.x;
  const int dpart = blockIdx.y;
  const int b     = blockIdx.z;
  const int tid  = threadIdx.x;
  const int wave = tid >> 6;
  const int lane = tid & 63;
  const int l15  = lane & 15;
  const int quad = lane >> 4;

  const int dblk0 = dpart * 16 + wave * 4;  // base 16-d tile index
  const unsigned short* Pq =
      Pt + (size_t)b * NTOK * NTOK + (size_t)q0b * 262144 + lane * 8;
  const unsigned short* Vb =
      Vt + (size_t)b * DDIM * NTOK + lane * 8;

  float rlv[4];
#pragma unroll
  for (int nt = 0; nt < 4; ++nt)
    rlv[nt] = 1.0f / lsum_g[(size_t)b * NTOK + q0b * 64 + nt * 16 + l15];

  f32x4 o[4][4];
#pragma unroll
  for (int i = 0; i < 4; ++i)
#pragma unroll
    for (int j = 0; j < 4; ++j) o[i][j] = (f32x4){0.f,0.f,0.f,0.f};

  bf16x8 pc[4], vc[4], pn[4], vn[4];
#pragma unroll
  for (int nt = 0; nt < 4; ++nt)
    pc[nt] = *(const bf16x8*)(Pq + (size_t)nt * 512);
#pragma unroll
  for (int mt = 0; mt < 4; ++mt)
    vc[mt] = *(const bf16x8*)(Vb + (size_t)(dblk0 + mt) * 65536);

#pragma unroll 2
  for (int ic = 0; ic < 127; ++ic) {
    // prefetch next chunk (fully coalesced 1-KB loads)
#pragma unroll
    for (int nt = 0; nt < 4; ++nt)
      pn[nt] = *(const bf16x8*)(Pq + (size_t)(ic + 1) * 2048 + (size_t)nt * 512);
#pragma unroll
    for (int mt = 0; mt < 4; ++mt)
      vn[mt] = *(const bf16x8*)(Vb + (size_t)(dblk0 + mt) * 65536 + (size_t)(ic + 1) * 512);
#pragma unroll
    for (int mt = 0; mt < 4; ++mt)
#pragma unroll
      for (int nt = 0; nt < 4; ++nt)
        o[mt][nt] = __builtin_amdgcn_mfma_f32_16x16x32_bf16(vc[mt], pc[nt], o[mt][nt], 0, 0, 0);
#pragma unroll
    for (int nt = 0; nt < 4; ++nt) pc[nt] = pn[nt];
#pragma unroll
    for (int mt = 0; mt < 4; ++mt) vc[mt] = vn[mt];
  }
#pragma unroll
  for (int mt = 0; mt < 4; ++mt)
#pragma unroll
    for (int nt = 0; nt < 4; ++nt)
      o[mt][nt] = __builtin_amdgcn_mfma_f32_16x16x32_bf16(vc[mt], pc[nt], o[mt][nt], 0, 0, 0);

  // epilogue: plain stores, 1/l folded in (per output column q).
  float* ob = out + ((size_t)b * DDIM + dpart * 256 + wave * 64) * NTOK + q0b * 64;
#pragma unroll
  for (int mt = 0; mt < 4; ++mt)
#pragma unroll
    for (int nt = 0; nt < 4; ++nt)
#pragma unroll
      for (int r = 0; r < 4; ++r)
        ob[(size_t)(mt * 16 + quad * 4 + r) * NTOK + nt * 16 + l15] =
            o[mt][nt][r] * rlv[nt];
}

// ---------------------------------------------------------------------------
// K4: scores[b][i] = sum_q Pexp[b][q][i] / l[b][q].  Tile-layout streaming.
// Grid (128 ic, NB); block exclusively owns i in [ic*32, +32) -> plain stores.
// ---------------------------------------------------------------------------
__global__ __launch_bounds__(256, 4) void colsum_k(
    const unsigned short* __restrict__ Pt,
    const float* __restrict__ lsum_g,
    float* __restrict__ scores_out)
{
  const int ic = blockIdx.x;
  const int b  = blockIdx.y;
  const int tid = threadIdx.x;
  const int wave = tid >> 6;
  const int lane = tid & 63;
  const int l15  = lane & 15;
  const int quad = lane >> 4;

  __shared__ float red[4][32];

  const unsigned short* Pb = Pt + (size_t)b * NTOK * NTOK + (size_t)ic * 2048 + lane * 8;
  const float* lb = lsum_g + (size_t)b * NTOK;

  float acc[8];
#pragma unroll
  for (int j = 0; j < 8; ++j) acc[j] = 0.f;

  for (int q0b = wave; q0b < 64; q0b += 4) {
    const unsigned short* src = Pb + (size_t)q0b * 262144;
#pragma unroll
    for (int nt = 0; nt < 4; ++nt) {
      const bf16x8 p = *(const bf16x8*)(src + (size_t)nt * 512);
      const float rl = 1.0f / lb[q0b * 64 + nt * 16 + l15];
#pragma unroll
      for (int j = 0; j < 8; ++j) acc[j] = fmaf(bf16_f32(p[j]), rl, acc[j]);
    }
  }
  // reduce over the 16 q-residues (l15) within the wave
#pragma unroll
  for (int j = 0; j < 8; ++j) {
    float v = acc[j];
    v += __shfl_xor(v, 1);
    v += __shfl_xor(v, 2);
    v += __shfl_xor(v, 4);
    v += __shfl_xor(v, 8);
    acc[j] = v;
  }
  if (l15 == 0) {
#pragma unroll
    for (int j = 0; j < 8; ++j) red[wave][quad * 8 + j] = acc[j];
  }
  __syncthreads();
  if (tid < 32)
    scores_out[(size_t)b * NTOK + ic * 32 + tid] =
        red[0][tid] + red[1][tid] + red[2][tid] + red[3][tid];
}

// ---------------------------------------------------------------------------
extern "C" void kernel_launch(void* const* d_in, const int* in_sizes, int n_in,
                              void* d_out, int out_size, void* d_ws, size_t ws_size,
                              hipStream_t stream) {
  const float* x  = (const float*)d_in[0];
  const float* Wk = (const float*)d_in[1];  // dict order: x, Wk, Wq, Wv
  const float* Wq = (const float*)d_in[2];
  const float* Wv = (const float*)d_in[3];

  float* out = (float*)d_out;
  float* scores_out = out + (size_t)NB * DDIM * NTOK;  // tail of d_out

  const size_t mat_elems = (size_t)NB * NTOK * DDIM;   // 8388608
  unsigned short* Qt = (unsigned short*)d_ws;
  unsigned short* Kt = Qt + mat_elems;
  unsigned short* Vt = Kt + mat_elems;
  float* lbuf = (float*)(Vt + mat_elems);              // 64 KB
  unsigned short* Pt = (unsigned short*)(lbuf + (size_t)NB * NTOK);  // 134.2 MB

  hipMemsetAsync(lbuf, 0, (size_t)NB * NTOK * sizeof(float), stream);

  dim3 g1(NTOK / 64, DDIM / 64, NB);
  qkv_proj<<<g1, 256, 0, stream>>>(x, Wq, Wk, Wv, Qt, Kt, Vt);

  dim3 g2(NTOK / 64, 4, NB);
  attn_lsum_p<<<g2, 256, 0, stream>>>(Qt, Kt, Pt, lbuf);

  dim3 g3(NTOK / 64, 2, NB);
  attn_pv<<<g3, 256, 0, stream>>>(Pt, Vt, lbuf, out);

  dim3 g4(128, NB);
  colsum_k<<<g4, 256, 0, stream>>>(Pt, lbuf, scores_out);
}